// Round 1
// baseline (147.966 us; speedup 1.0000x reference)
//
#include <hip/hip_runtime.h>

#define NDOF 7
#define BLK 256
#define CST_STRIDE 24               // floats per dof block (= 6 float4)
#define CST_TOT (NDOF * CST_STRIDE) // 168

// ---------- tiny vec3 ----------
struct V3 { float x, y, z; };
__device__ __forceinline__ V3 operator+(V3 a, V3 b) { return {a.x + b.x, a.y + b.y, a.z + b.z}; }
__device__ __forceinline__ V3 operator-(V3 a, V3 b) { return {a.x - b.x, a.y - b.y, a.z - b.z}; }
__device__ __forceinline__ V3 operator*(float s, V3 a) { return {s * a.x, s * a.y, s * a.z}; }
__device__ __forceinline__ V3 cross(V3 a, V3 b) {
    return {a.y * b.z - a.z * b.y, a.z * b.x - a.x * b.z, a.x * b.y - a.y * b.x};
}
__device__ __forceinline__ float dot(V3 a, V3 b) { return a.x * b.x + a.y * b.y + a.z * b.z; }

// AX: 0 = +z, 1 = +y, 2 = -y   (joint_axes is a literal in the reference)
template <int AX>
__device__ __forceinline__ void make_R(V3 Fc0, V3 Fc1, V3 Fc2, float s, float c,
                                       V3& R0, V3& R1, V3& R2) {
    if (AX == 0) {          // Rq_z cols: (c,s,0), (-s,c,0), (0,0,1)
        R0 = c * Fc0 + s * Fc1;
        R1 = c * Fc1 - s * Fc0;
        R2 = Fc2;
    } else if (AX == 1) {   // Rq_y cols: (c,0,-s), (0,1,0), (s,0,c)
        R0 = c * Fc0 - s * Fc2;
        R1 = Fc1;
        R2 = s * Fc0 + c * Fc2;
    } else {                // Rq_-y cols: (c,0,s), (0,1,0), (-s,0,c)
        R0 = c * Fc0 + s * Fc2;
        R1 = Fc1;
        R2 = c * Fc2 - s * Fc0;
    }
}

// fwd: computes this link's fl/fa (local frame) and updates v/a state in place.
template <int AX>
__device__ __forceinline__ void fwd_step(const float4* C4, float s, float c,
                                         float qd, float qdd, V3& vl, V3& va, V3& al,
                                         V3& aa, V3& fl, V3& fa) {
    const float4 A0 = C4[0], A1 = C4[1], A2 = C4[2], A3 = C4[3], A4 = C4[4], A5 = C4[5];
    const V3 Fc0{A0.x, A0.y, A0.z};
    const V3 Fc1{A0.w, A1.x, A1.y};
    const V3 Fc2{A1.z, A1.w, A2.x};
    const V3 p{A2.y, A2.z, A2.w};
    const float I00 = A3.x, I01 = A3.y, I02 = A3.z, I11 = A3.w, I12 = A4.x, I22 = A4.y;
    const float m = A4.z;
    const V3 mc{A4.w, A5.x, A5.y};

    V3 R0, R1, R2;
    make_R<AX>(Fc0, Fc1, Fc2, s, c, R0, R1, R2);

    // Rt(vl) + cross(-Rt p, Rt va) == Rt(vl + va x p)
    V3 w1 = vl + cross(va, p);
    V3 w2 = al + cross(aa, p);
    V3 nvl{dot(R0, w1), dot(R1, w1), dot(R2, w1)};
    V3 nva{dot(R0, va), dot(R1, va), dot(R2, va)};
    V3 nal{dot(R0, w2), dot(R1, w2), dot(R2, w2)};
    V3 naa{dot(R0, aa), dot(R1, aa), dot(R2, aa)};

    if (AX == 0) {          // jv=(0,0,qd): cross(v,jv)=(v.y*qd,-v.x*qd,0)
        va = {nva.x, nva.y, nva.z + qd};
        aa = {naa.x + va.y * qd, naa.y - va.x * qd, naa.z + qdd};
        vl = nvl;
        al = {nal.x + vl.y * qd, nal.y - vl.x * qd, nal.z};
    } else if (AX == 1) {   // jv=(0,qd,0): cross(v,jv)=(-v.z*qd,0,v.x*qd)
        va = {nva.x, nva.y + qd, nva.z};
        aa = {naa.x - va.z * qd, naa.y + qdd, naa.z + va.x * qd};
        vl = nvl;
        al = {nal.x - vl.z * qd, nal.y, nal.z + vl.x * qd};
    } else {                // jv=(0,-qd,0): cross(v,jv)=(v.z*qd,0,-v.x*qd)
        va = {nva.x, nva.y - qd, nva.z};
        aa = {naa.x + va.z * qd, naa.y - qdd, naa.z - va.x * qd};
        vl = nvl;
        al = {nal.x + vl.z * qd, nal.y, nal.z - vl.x * qd};
    }

    V3 Ial = m * al + cross(aa, mc);
    V3 Iaa = V3{I00 * aa.x + I01 * aa.y + I02 * aa.z,
                I01 * aa.x + I11 * aa.y + I12 * aa.z,
                I02 * aa.x + I12 * aa.y + I22 * aa.z} + cross(mc, al);
    V3 Ivl = m * vl + cross(va, mc);
    V3 Iva = V3{I00 * va.x + I01 * va.y + I02 * va.z,
                I01 * va.x + I11 * va.y + I12 * va.z,
                I02 * va.x + I12 * va.y + I22 * va.z} + cross(mc, vl);
    fl = Ial + cross(va, Ivl);
    fa = Iaa + cross(va, Iva) + cross(vl, Ivl);
}

// propagate a (force, torque) pair one frame down: (tl,ta) in frame d ->
// frame d-1, using link d's (R, p).  Linear in (tl,ta), so per-link
// propagation sums to the reference's reverse-scan carry exactly.
template <int AX>
__device__ __forceinline__ void prop_step(const float4* C4, float s, float c,
                                          V3& tl, V3& ta) {
    const float4 A0 = C4[0], A1 = C4[1], A2 = C4[2];   // only F and p needed
    const V3 Fc0{A0.x, A0.y, A0.z};
    const V3 Fc1{A0.w, A1.x, A1.y};
    const V3 Fc2{A1.z, A1.w, A2.x};
    const V3 p{A2.y, A2.z, A2.w};
    V3 R0, R1, R2;
    make_R<AX>(Fc0, Fc1, Fc2, s, c, R0, R1, R2);
    V3 nl = tl.x * R0 + tl.y * R1 + tl.z * R2;   // R @ tl (columns)
    V3 na = ta.x * R0 + ta.y * R1 + ta.z * R2 + cross(p, nl);
    tl = nl;
    ta = na;
}

template <int AX>
__device__ __forceinline__ float taudot(V3 ta) {
    if (AX == 0) return ta.z;
    else if (AX == 1) return ta.y;
    else return -ta.y;
}

// ---------- main kernel ----------
// Single-phase O(n^2) RNEA: as each link's wrench is produced it is
// immediately propagated down to the base, accumulating tau[d] at each
// frame.  Eliminates the fwd->bwd LDS parking (33.8 KB -> 0.7 KB), the
// mid-kernel barrier, and the cross-phase register liveness that forced
// the previous 2-phase design.  +14 extra frame transforms/thread (~+30%
// VALU) traded for ~2x occupancy and zero LDS traffic.
// Prep (constant packing) is folded in per-block: 7 threads, ~40 FLOPs
// each, sources L2-resident after block 0 — removes the rnea_prep launch
// and its graph dependency.
__global__ __launch_bounds__(BLK) void rnea_main(
    const float* __restrict__ q_g, const float* __restrict__ qd_g,
    const float* __restrict__ qdd_g,
    const float* __restrict__ rot_fix, const float* __restrict__ trans_fix,
    const float* __restrict__ mass_g, const float* __restrict__ com_g,
    const float* __restrict__ inertia_g, const float* __restrict__ damping_g,
    float* __restrict__ out, int nbatch) {
    __shared__ __align__(16) float sC[CST_TOT];
    const int t = threadIdx.x;
    const int row = blockIdx.x * BLK + t;
    const bool ok = row < nbatch;
    const size_t go = (size_t)row * NDOF;

    // inline prep: per dof d (24 floats):
    // [0:9) F columns, [9:12) p, [12:18) Io6, [18] m, [19:22) mc, [22] damp
    if (t < NDOF) {
        const int d = t;
        float* o = sC + d * CST_STRIDE;
        const float* F = rot_fix + (1 + d) * 9;
#pragma unroll
        for (int j = 0; j < 3; j++)
#pragma unroll
            for (int i = 0; i < 3; i++) o[j * 3 + i] = F[i * 3 + j];  // column-major
#pragma unroll
        for (int i = 0; i < 3; i++) o[9 + i] = trans_fix[(1 + d) * 3 + i];
        const float m = mass_g[1 + d];
        const float c0 = com_g[(1 + d) * 3 + 0];
        const float c1 = com_g[(1 + d) * 3 + 1];
        const float c2 = com_g[(1 + d) * 3 + 2];
        const float* I = inertia_g + (1 + d) * 9;
        o[12] = I[0] + m * (c1 * c1 + c2 * c2);
        o[13] = I[1] - m * c0 * c1;
        o[14] = I[2] - m * c0 * c2;
        o[15] = I[4] + m * (c0 * c0 + c2 * c2);
        o[16] = I[5] - m * c1 * c2;
        o[17] = I[8] + m * (c0 * c0 + c1 * c1);
        o[18] = m;
        o[19] = m * c0;
        o[20] = m * c1;
        o[21] = m * c2;
        o[22] = damping_g[d];
        o[23] = 0.f;
    }

    float qd[NDOF], ss[NDOF], cc[NDOF], qdd[NDOF];
    if (ok) {
        float q[NDOF];
#pragma unroll
        for (int d = 0; d < NDOF; d++) q[d] = q_g[go + d];
#pragma unroll
        for (int d = 0; d < NDOF; d++) qd[d] = qd_g[go + d];
#pragma unroll
        for (int d = 0; d < NDOF; d++) qdd[d] = qdd_g[go + d];
        // all transcendentals upfront: independent pairs overlap in the pipe
#pragma unroll
        for (int d = 0; d < NDOF; d++) { ss[d] = __sinf(q[d]); cc[d] = __cosf(q[d]); }
    }

    __syncthreads();   // sC ready (only barrier in the kernel)

    if (ok) {
        const float4* C4 = reinterpret_cast<const float4*>(sC);
        V3 vl{0.f, 0.f, 0.f}, va{0.f, 0.f, 0.f}, al{0.f, 0.f, 9.81f}, aa{0.f, 0.f, 0.f};
        V3 fl, fa, tl, ta;
        float tau0, tau1, tau2, tau3, tau4, tau5, tau6;

        // axis sequence: z, y, z, -y, z, y, z  -> AX template ids 0,1,0,2,0,1,0
        // link 0
        fwd_step<0>(C4 + 0 * 6, ss[0], cc[0], qd[0], qdd[0], vl, va, al, aa, fl, fa);
        tau0 = taudot<0>(fa);

        // link 1
        fwd_step<1>(C4 + 1 * 6, ss[1], cc[1], qd[1], qdd[1], vl, va, al, aa, fl, fa);
        tau1 = taudot<1>(fa);
        tl = fl; ta = fa;
        prop_step<1>(C4 + 1 * 6, ss[1], cc[1], tl, ta); tau0 += taudot<0>(ta);

        // link 2
        fwd_step<0>(C4 + 2 * 6, ss[2], cc[2], qd[2], qdd[2], vl, va, al, aa, fl, fa);
        tau2 = taudot<0>(fa);
        tl = fl; ta = fa;
        prop_step<0>(C4 + 2 * 6, ss[2], cc[2], tl, ta); tau1 += taudot<1>(ta);
        prop_step<1>(C4 + 1 * 6, ss[1], cc[1], tl, ta); tau0 += taudot<0>(ta);

        // link 3
        fwd_step<2>(C4 + 3 * 6, ss[3], cc[3], qd[3], qdd[3], vl, va, al, aa, fl, fa);
        tau3 = taudot<2>(fa);
        tl = fl; ta = fa;
        prop_step<2>(C4 + 3 * 6, ss[3], cc[3], tl, ta); tau2 += taudot<0>(ta);
        prop_step<0>(C4 + 2 * 6, ss[2], cc[2], tl, ta); tau1 += taudot<1>(ta);
        prop_step<1>(C4 + 1 * 6, ss[1], cc[1], tl, ta); tau0 += taudot<0>(ta);

        // link 4
        fwd_step<0>(C4 + 4 * 6, ss[4], cc[4], qd[4], qdd[4], vl, va, al, aa, fl, fa);
        tau4 = taudot<0>(fa);
        tl = fl; ta = fa;
        prop_step<0>(C4 + 4 * 6, ss[4], cc[4], tl, ta); tau3 += taudot<2>(ta);
        prop_step<2>(C4 + 3 * 6, ss[3], cc[3], tl, ta); tau2 += taudot<0>(ta);
        prop_step<0>(C4 + 2 * 6, ss[2], cc[2], tl, ta); tau1 += taudot<1>(ta);
        prop_step<1>(C4 + 1 * 6, ss[1], cc[1], tl, ta); tau0 += taudot<0>(ta);

        // link 5
        fwd_step<1>(C4 + 5 * 6, ss[5], cc[5], qd[5], qdd[5], vl, va, al, aa, fl, fa);
        tau5 = taudot<1>(fa);
        tl = fl; ta = fa;
        prop_step<1>(C4 + 5 * 6, ss[5], cc[5], tl, ta); tau4 += taudot<0>(ta);
        prop_step<0>(C4 + 4 * 6, ss[4], cc[4], tl, ta); tau3 += taudot<2>(ta);
        prop_step<2>(C4 + 3 * 6, ss[3], cc[3], tl, ta); tau2 += taudot<0>(ta);
        prop_step<0>(C4 + 2 * 6, ss[2], cc[2], tl, ta); tau1 += taudot<1>(ta);
        prop_step<1>(C4 + 1 * 6, ss[1], cc[1], tl, ta); tau0 += taudot<0>(ta);

        // link 6
        fwd_step<0>(C4 + 6 * 6, ss[6], cc[6], qd[6], qdd[6], vl, va, al, aa, fl, fa);
        tau6 = taudot<0>(fa);
        tl = fl; ta = fa;
        prop_step<0>(C4 + 6 * 6, ss[6], cc[6], tl, ta); tau5 += taudot<1>(ta);
        prop_step<1>(C4 + 5 * 6, ss[5], cc[5], tl, ta); tau4 += taudot<0>(ta);
        prop_step<0>(C4 + 4 * 6, ss[4], cc[4], tl, ta); tau3 += taudot<2>(ta);
        prop_step<2>(C4 + 3 * 6, ss[3], cc[3], tl, ta); tau2 += taudot<0>(ta);
        prop_step<0>(C4 + 2 * 6, ss[2], cc[2], tl, ta); tau1 += taudot<1>(ta);
        prop_step<1>(C4 + 1 * 6, ss[1], cc[1], tl, ta); tau0 += taudot<0>(ta);

        float tau[NDOF] = {tau0, tau1, tau2, tau3, tau4, tau5, tau6};
#pragma unroll
        for (int d = 0; d < NDOF; d++)
            out[go + d] = tau[d] + sC[d * CST_STRIDE + 22] * qd[d];
    }
}

extern "C" void kernel_launch(void* const* d_in, const int* in_sizes, int n_in,
                              void* d_out, int out_size, void* d_ws, size_t ws_size,
                              hipStream_t stream) {
    const float* q = (const float*)d_in[0];
    const float* qd = (const float*)d_in[1];
    const float* qdd = (const float*)d_in[2];
    const float* rot_fix = (const float*)d_in[3];
    const float* trans_fix = (const float*)d_in[4];
    // d_in[5] = joint_axes: compile-time constant in the reference (z,y,z,-y,z,y,z)
    const float* mass = (const float*)d_in[6];
    const float* com = (const float*)d_in[7];
    const float* inertia = (const float*)d_in[8];
    const float* damping = (const float*)d_in[9];
    float* out = (float*)d_out;

    const int n_elem = in_sizes[0];  // B * 7
    const int B = n_elem / NDOF;
    const int grid = (B + BLK - 1) / BLK;

    rnea_main<<<grid, BLK, 0, stream>>>(q, qd, qdd, rot_fix, trans_fix, mass, com,
                                        inertia, damping, out, B);
}

// Round 2
// 134.527 us; speedup vs baseline: 1.0999x; 1.0999x over previous
//
#include <hip/hip_runtime.h>

#define NDOF 7
#define BLK 256
#define CST_STRIDE 24               // floats per dof block
#define CST_TOT (NDOF * CST_STRIDE) // 168

// ---------- tiny vec3 ----------
struct V3 { float x, y, z; };
__device__ __forceinline__ V3 operator+(V3 a, V3 b) { return {a.x + b.x, a.y + b.y, a.z + b.z}; }
__device__ __forceinline__ V3 operator-(V3 a, V3 b) { return {a.x - b.x, a.y - b.y, a.z - b.z}; }
__device__ __forceinline__ V3 operator*(float s, V3 a) { return {s * a.x, s * a.y, s * a.z}; }
__device__ __forceinline__ V3 cross(V3 a, V3 b) {
    return {a.y * b.z - a.z * b.y, a.z * b.x - a.x * b.z, a.x * b.y - a.y * b.x};
}
__device__ __forceinline__ float dot(V3 a, V3 b) { return a.x * b.x + a.y * b.y + a.z * b.z; }

// ---------- prep: pack per-dof constants into d_ws ----------
// per dof d (24 floats): [0:9) F columns (column-major), [9:12) p,
// [12:18) Io6=I00,I01,I02,I11,I12,I22, [18] m, [19:22) mc, [22] damp, [23] pad
__global__ void rnea_prep(const float* __restrict__ rot_fix,
                          const float* __restrict__ trans_fix,
                          const float* __restrict__ mass_g,
                          const float* __restrict__ com_g,
                          const float* __restrict__ inertia_g,
                          const float* __restrict__ damping_g,
                          float* __restrict__ cst) {
    const int d = threadIdx.x;
    if (d >= NDOF) return;
    float* o = cst + d * CST_STRIDE;
    const float* F = rot_fix + (1 + d) * 9;
#pragma unroll
    for (int j = 0; j < 3; j++)
#pragma unroll
        for (int i = 0; i < 3; i++) o[j * 3 + i] = F[i * 3 + j];  // column-major
#pragma unroll
    for (int i = 0; i < 3; i++) o[9 + i] = trans_fix[(1 + d) * 3 + i];
    const float m = mass_g[1 + d];
    const float c0 = com_g[(1 + d) * 3 + 0];
    const float c1 = com_g[(1 + d) * 3 + 1];
    const float c2 = com_g[(1 + d) * 3 + 2];
    const float* I = inertia_g + (1 + d) * 9;
    o[12] = I[0] + m * (c1 * c1 + c2 * c2);
    o[13] = I[1] - m * c0 * c1;
    o[14] = I[2] - m * c0 * c2;
    o[15] = I[4] + m * (c0 * c0 + c2 * c2);
    o[16] = I[5] - m * c1 * c2;
    o[17] = I[8] + m * (c0 * c0 + c1 * c1);
    o[18] = m;
    o[19] = m * c0;
    o[20] = m * c1;
    o[21] = m * c2;
    o[22] = damping_g[d];
    o[23] = 0.f;
}

// AX: 0 = +z, 1 = +y, 2 = -y   (joint_axes is a literal in the reference)
template <int AX>
__device__ __forceinline__ void make_R(V3 Fc0, V3 Fc1, V3 Fc2, float s, float c,
                                       V3& R0, V3& R1, V3& R2) {
    if (AX == 0) {          // Rq_z cols: (c,s,0), (-s,c,0), (0,0,1)
        R0 = c * Fc0 + s * Fc1;
        R1 = c * Fc1 - s * Fc0;
        R2 = Fc2;
    } else if (AX == 1) {   // Rq_y cols: (c,0,-s), (0,1,0), (s,0,c)
        R0 = c * Fc0 - s * Fc2;
        R1 = Fc1;
        R2 = s * Fc0 + c * Fc2;
    } else {                // Rq_-y cols: (c,0,s), (0,1,0), (-s,0,c)
        R0 = c * Fc0 + s * Fc2;
        R1 = Fc1;
        R2 = c * Fc2 - s * Fc0;
    }
}

// fwd: computes this link's fl/fa (local frame) and updates v/a state in place.
// Constants come in via a UNIFORM global pointer with compile-time indices ->
// hipcc emits s_load (SMEM); they live in SGPRs, costing zero VGPRs.
template <int AX>
__device__ __forceinline__ void fwd_step(const float* __restrict__ C, float s, float c,
                                         float qd, float qdd, V3& vl, V3& va, V3& al,
                                         V3& aa, V3& fl, V3& fa) {
    const V3 Fc0{C[0], C[1], C[2]};
    const V3 Fc1{C[3], C[4], C[5]};
    const V3 Fc2{C[6], C[7], C[8]};
    const V3 p{C[9], C[10], C[11]};
    const float I00 = C[12], I01 = C[13], I02 = C[14], I11 = C[15], I12 = C[16], I22 = C[17];
    const float m = C[18];
    const V3 mc{C[19], C[20], C[21]};

    V3 R0, R1, R2;
    make_R<AX>(Fc0, Fc1, Fc2, s, c, R0, R1, R2);

    // Rt(vl) + cross(-Rt p, Rt va) == Rt(vl + va x p)
    V3 w1 = vl + cross(va, p);
    V3 w2 = al + cross(aa, p);
    V3 nvl{dot(R0, w1), dot(R1, w1), dot(R2, w1)};
    V3 nva{dot(R0, va), dot(R1, va), dot(R2, va)};
    V3 nal{dot(R0, w2), dot(R1, w2), dot(R2, w2)};
    V3 naa{dot(R0, aa), dot(R1, aa), dot(R2, aa)};

    if (AX == 0) {          // jv=(0,0,qd): cross(v,jv)=(v.y*qd,-v.x*qd,0)
        va = {nva.x, nva.y, nva.z + qd};
        aa = {naa.x + va.y * qd, naa.y - va.x * qd, naa.z + qdd};
        vl = nvl;
        al = {nal.x + vl.y * qd, nal.y - vl.x * qd, nal.z};
    } else if (AX == 1) {   // jv=(0,qd,0): cross(v,jv)=(-v.z*qd,0,v.x*qd)
        va = {nva.x, nva.y + qd, nva.z};
        aa = {naa.x - va.z * qd, naa.y + qdd, naa.z + va.x * qd};
        vl = nvl;
        al = {nal.x - vl.z * qd, nal.y, nal.z + vl.x * qd};
    } else {                // jv=(0,-qd,0): cross(v,jv)=(v.z*qd,0,-v.x*qd)
        va = {nva.x, nva.y - qd, nva.z};
        aa = {naa.x + va.z * qd, naa.y - qdd, naa.z - va.x * qd};
        vl = nvl;
        al = {nal.x + vl.z * qd, nal.y, nal.z - vl.x * qd};
    }

    V3 Ial = m * al + cross(aa, mc);
    V3 Iaa = V3{I00 * aa.x + I01 * aa.y + I02 * aa.z,
                I01 * aa.x + I11 * aa.y + I12 * aa.z,
                I02 * aa.x + I12 * aa.y + I22 * aa.z} + cross(mc, al);
    V3 Ivl = m * vl + cross(va, mc);
    V3 Iva = V3{I00 * va.x + I01 * va.y + I02 * va.z,
                I01 * va.x + I11 * va.y + I12 * va.z,
                I02 * va.x + I12 * va.y + I22 * va.z} + cross(mc, vl);
    fl = Ial + cross(va, Ivl);
    fa = Iaa + cross(va, Iva) + cross(vl, Ivl);
}

// bwd: consumes fl/fa by value (register-parked), updates carry, returns tau.
template <int AX>
__device__ __forceinline__ float bwd_core(const float* __restrict__ C, float s, float c,
                                          V3 fl, V3 fa, V3& cl, V3& ca) {
    const V3 Fc0{C[0], C[1], C[2]};
    const V3 Fc1{C[3], C[4], C[5]};
    const V3 Fc2{C[6], C[7], C[8]};
    const V3 p{C[9], C[10], C[11]};

    V3 tl = fl + cl;
    V3 ta = fa + ca;
    float tau;
    if (AX == 0) tau = ta.z;
    else if (AX == 1) tau = ta.y;
    else tau = -ta.y;

    V3 R0, R1, R2;
    make_R<AX>(Fc0, Fc1, Fc2, s, c, R0, R1, R2);
    V3 nl = tl.x * R0 + tl.y * R1 + tl.z * R2;   // R @ tl (columns)
    V3 na = ta.x * R0 + ta.y * R1 + ta.z * R2 + cross(p, nl);
    cl = nl;
    ca = na;
    return tau;
}

// ---------- main kernel ----------
// O(n) two-pass RNEA, fully in registers:
//  - constants are wave-uniform scalar loads (SGPRs, zero VGPR cost) -> no
//    LDS, no barrier, and the round-1 pathology (compiler hoisting 42x
//    float4 of LDS constants into VGPRs -> 216 VGPR, 10% occupancy) is
//    structurally impossible.
//  - fl/fa for all 7 links park in named registers across fwd->bwd (42
//    floats), affordable now that constants are off the VGPR budget.
//  - no divergence in the body: loads use a clamped row, only the final
//    store is guarded -> keeps control flow uniform so SMEM promotion of
//    the constant loads is legal.
__global__ __launch_bounds__(BLK) void rnea_main(
    const float* __restrict__ q_g, const float* __restrict__ qd_g,
    const float* __restrict__ qdd_g, const float* __restrict__ cst,
    float* __restrict__ out, int nbatch) {
    const int t = threadIdx.x;
    const int row = blockIdx.x * BLK + t;
    const int rowc = row < nbatch ? row : (nbatch - 1);  // clamp: branch-free loads
    const size_t go = (size_t)rowc * NDOF;

    float q[NDOF], qd[NDOF], qdd[NDOF], ss[NDOF], cc[NDOF];
#pragma unroll
    for (int d = 0; d < NDOF; d++) q[d] = q_g[go + d];
#pragma unroll
    for (int d = 0; d < NDOF; d++) qd[d] = qd_g[go + d];
#pragma unroll
    for (int d = 0; d < NDOF; d++) qdd[d] = qdd_g[go + d];
#pragma unroll
    for (int d = 0; d < NDOF; d++) { ss[d] = __sinf(q[d]); cc[d] = __cosf(q[d]); }

    V3 vl{0.f, 0.f, 0.f}, va{0.f, 0.f, 0.f}, al{0.f, 0.f, 9.81f}, aa{0.f, 0.f, 0.f};
    V3 fl0, fa0, fl1, fa1, fl2, fa2, fl3, fa3, fl4, fa4, fl5, fa5, fl6, fa6;

    // axis sequence: z, y, z, -y, z, y, z -> AX ids 0,1,0,2,0,1,0
    fwd_step<0>(cst + 0 * CST_STRIDE, ss[0], cc[0], qd[0], qdd[0], vl, va, al, aa, fl0, fa0);
    fwd_step<1>(cst + 1 * CST_STRIDE, ss[1], cc[1], qd[1], qdd[1], vl, va, al, aa, fl1, fa1);
    fwd_step<0>(cst + 2 * CST_STRIDE, ss[2], cc[2], qd[2], qdd[2], vl, va, al, aa, fl2, fa2);
    fwd_step<2>(cst + 3 * CST_STRIDE, ss[3], cc[3], qd[3], qdd[3], vl, va, al, aa, fl3, fa3);
    fwd_step<0>(cst + 4 * CST_STRIDE, ss[4], cc[4], qd[4], qdd[4], vl, va, al, aa, fl4, fa4);
    fwd_step<1>(cst + 5 * CST_STRIDE, ss[5], cc[5], qd[5], qdd[5], vl, va, al, aa, fl5, fa5);
    fwd_step<0>(cst + 6 * CST_STRIDE, ss[6], cc[6], qd[6], qdd[6], vl, va, al, aa, fl6, fa6);

    V3 cl{0.f, 0.f, 0.f}, ca{0.f, 0.f, 0.f};
    float tau[NDOF];
    tau[6] = bwd_core<0>(cst + 6 * CST_STRIDE, ss[6], cc[6], fl6, fa6, cl, ca);
    tau[5] = bwd_core<1>(cst + 5 * CST_STRIDE, ss[5], cc[5], fl5, fa5, cl, ca);
    tau[4] = bwd_core<0>(cst + 4 * CST_STRIDE, ss[4], cc[4], fl4, fa4, cl, ca);
    tau[3] = bwd_core<2>(cst + 3 * CST_STRIDE, ss[3], cc[3], fl3, fa3, cl, ca);
    tau[2] = bwd_core<0>(cst + 2 * CST_STRIDE, ss[2], cc[2], fl2, fa2, cl, ca);
    tau[1] = bwd_core<1>(cst + 1 * CST_STRIDE, ss[1], cc[1], fl1, fa1, cl, ca);
    tau[0] = bwd_core<0>(cst + 0 * CST_STRIDE, ss[0], cc[0], fl0, fa0, cl, ca);

    if (row < nbatch) {
#pragma unroll
        for (int d = 0; d < NDOF; d++)
            out[go + d] = tau[d] + cst[d * CST_STRIDE + 22] * qd[d];
    }
}

extern "C" void kernel_launch(void* const* d_in, const int* in_sizes, int n_in,
                              void* d_out, int out_size, void* d_ws, size_t ws_size,
                              hipStream_t stream) {
    const float* q = (const float*)d_in[0];
    const float* qd = (const float*)d_in[1];
    const float* qdd = (const float*)d_in[2];
    const float* rot_fix = (const float*)d_in[3];
    const float* trans_fix = (const float*)d_in[4];
    // d_in[5] = joint_axes: compile-time constant in the reference (z,y,z,-y,z,y,z)
    const float* mass = (const float*)d_in[6];
    const float* com = (const float*)d_in[7];
    const float* inertia = (const float*)d_in[8];
    const float* damping = (const float*)d_in[9];
    float* out = (float*)d_out;
    float* cst = (float*)d_ws;  // 7*24*4 = 672 B

    const int n_elem = in_sizes[0];  // B * 7
    const int B = n_elem / NDOF;
    const int grid = (B + BLK - 1) / BLK;

    rnea_prep<<<1, 64, 0, stream>>>(rot_fix, trans_fix, mass, com, inertia, damping, cst);
    rnea_main<<<grid, BLK, 0, stream>>>(q, qd, qdd, cst, out, B);
}